// Round 1
// baseline (353.588 us; speedup 1.0000x reference)
//
#include <hip/hip_runtime.h>
#include <stdint.h>

#define BB 4
#define CC 256
#define NN 4096
#define GG 8

typedef unsigned short u16;
typedef __attribute__((ext_vector_type(4))) float f32x4;
typedef __attribute__((ext_vector_type(8))) short s16x8;
typedef __attribute__((ext_vector_type(4))) u16 u16x4;
typedef __attribute__((ext_vector_type(8))) u16 u16x8;

__device__ __forceinline__ u16 f2bf(float f) {
  union { float f; uint32_t u; } v; v.f = f;
  return (u16)((v.u + 0x7FFFu + ((v.u >> 16) & 1u)) >> 16);
}

__device__ __forceinline__ void async16(const void* g, void* l) {
  __builtin_amdgcn_global_load_lds(
      (const __attribute__((address_space(1))) void*)g,
      (__attribute__((address_space(3))) void*)l, 16, 0, 0);
}

// ---------------- weight f32 -> bf16 ----------------
__global__ __launch_bounds__(256) void wcvt_kernel(
    const float* __restrict__ w0, const float* __restrict__ w1,
    const float* __restrict__ w2, const float* __restrict__ w3,
    u16* __restrict__ dst) {
  const float* src = (blockIdx.y == 0) ? w0 : (blockIdx.y == 1) ? w1
                   : (blockIdx.y == 2) ? w2 : w3;
  int i = blockIdx.x * 256 + threadIdx.x;  // 64 blocks -> 16384 f32x4 = 65536 f32
  f32x4 v = ((const f32x4*)src)[i];
  u16x4 o;
  o[0] = f2bf(v[0]); o[1] = f2bf(v[1]); o[2] = f2bf(v[2]); o[3] = f2bf(v[3]);
  ((u16x4*)(dst + (size_t)blockIdx.y * 65536))[i] = o;
}

// ---------------- GroupNorm stats: 32 blocks = (b,g) ----------------
__global__ __launch_bounds__(256) void gn_stats_kernel(
    const float* __restrict__ x, float* __restrict__ stats) {
  int bg = blockIdx.x;  // b*8+g ; 32 ch * 4096 = 131072 contiguous floats
  const f32x4* xp = (const f32x4*)(x + (size_t)bg * 131072);
  float s = 0.f, ss = 0.f;
  for (int i = threadIdx.x; i < 32768; i += 256) {
    f32x4 v = xp[i];
    s += v[0] + v[1] + v[2] + v[3];
    ss += v[0]*v[0] + v[1]*v[1] + v[2]*v[2] + v[3]*v[3];
  }
  for (int d = 1; d < 64; d <<= 1) {
    s += __shfl_xor(s, d, 64);
    ss += __shfl_xor(ss, d, 64);
  }
  __shared__ float red[8];
  int w = threadIdx.x >> 6, lane = threadIdx.x & 63;
  if (lane == 0) { red[w*2] = s; red[w*2+1] = ss; }
  __syncthreads();
  if (threadIdx.x == 0) {
    float S = red[0]+red[2]+red[4]+red[6], SS = red[1]+red[3]+red[5]+red[7];
    float mean = S * (1.0f/131072.0f);
    float var = SS * (1.0f/131072.0f) - mean*mean;
    stats[bg*2]   = mean;
    stats[bg*2+1] = rsqrtf(var + 1e-5f);
  }
}

// -------- GN apply + transpose to token-major bf16 xn[b][n][c] --------
__global__ __launch_bounds__(256) void gn_apply_kernel(
    const float* __restrict__ x, const float* __restrict__ stats,
    const float* __restrict__ gamma, const float* __restrict__ beta,
    u16* __restrict__ xn) {
  int b = blockIdx.y, n0 = blockIdx.x * 64, t = threadIdx.x;
  __shared__ u16 tile[16384];  // [256 c][64 n] bf16, XOR-swizzled
  for (int p = 0; p < 16; ++p) {
    int c = p*16 + (t >> 4);
    int n4 = (t & 15) * 4;
    f32x4 v = *(const f32x4*)(x + ((size_t)b*CC + c)*NN + n0 + n4);
    int sidx = (b*GG + (c >> 5)) * 2;
    float mean = stats[sidx], rstd = stats[sidx+1];
    float ga = gamma[c] * rstd;
    float be = beta[c] - mean * ga;
    u16x4 o;
    o[0]=f2bf(v[0]*ga+be); o[1]=f2bf(v[1]*ga+be);
    o[2]=f2bf(v[2]*ga+be); o[3]=f2bf(v[3]*ga+be);
    int swz = (((c & 7) ^ ((c >> 3) & 7)) << 4);
    *(u16x4*)((char*)tile + c*128 + ((n4*2) ^ swz)) = o;
  }
  __syncthreads();
  for (int p = 0; p < 8; ++p) {
    int n = p*8 + (t >> 5);
    int c0 = (t & 31) * 8;
    u16x8 o;
#pragma unroll
    for (int j = 0; j < 8; ++j) {
      int c = c0 + j;
      int swz = (((c & 7) ^ ((c >> 3) & 7)) << 4);
      o[j] = *(const u16*)((const char*)tile + c*128 + ((n*2) ^ swz));
    }
    *(u16x8*)(xn + ((size_t)b*NN + n0 + n)*CC + c0) = o;
  }
}

// -------- GEMM token-major out: Y[b][n][o] = X[b][n][:]·W[o][:] + bias --------
__global__ __launch_bounds__(256) void gemm_tm_kernel(
    const u16* __restrict__ X, const u16* __restrict__ W,
    const float* __restrict__ bias, u16* __restrict__ Y) {
  int b = blockIdx.z, n0 = blockIdx.x * 64, o0 = blockIdx.y * 64;
  int lane = threadIdx.x & 63, w = threadIdx.x >> 6;
  int hi = lane >> 4, lo = lane & 15;
  const u16* xp = X + ((size_t)b*NN + n0 + w*16 + lo)*CC + hi*8;
  f32x4 acc[4] = {};
  for (int kc = 0; kc < 8; ++kc) {
    s16x8 a = *(const s16x8*)(xp + kc*32);
#pragma unroll
    for (int j = 0; j < 4; ++j) {
      s16x8 bb = *(const s16x8*)(W + (size_t)(o0 + j*16 + lo)*CC + kc*32 + hi*8);
      acc[j] = __builtin_amdgcn_mfma_f32_16x16x32_bf16(a, bb, acc[j], 0, 0, 0);
    }
  }
#pragma unroll
  for (int j = 0; j < 4; ++j) {
    int oc = o0 + j*16 + lo;
    float bv = bias[oc];
#pragma unroll
    for (int r = 0; r < 4; ++r) {
      int nn = n0 + w*16 + hi*4 + r;
      Y[((size_t)b*NN + nn)*CC + oc] = f2bf(acc[j][r] + bv);
    }
  }
}

// -------- GEMM channel-major out: Y[b][o][m] = W[o][:]·X[b][m][:] + bias --------
__global__ __launch_bounds__(256) void gemm_cm_bf16_kernel(
    const u16* __restrict__ X, const u16* __restrict__ W,
    const float* __restrict__ bias, u16* __restrict__ Ycm) {
  int b = blockIdx.z, m0 = blockIdx.x * 64, o0 = blockIdx.y * 64;
  int lane = threadIdx.x & 63, w = threadIdx.x >> 6;
  int hi = lane >> 4, lo = lane & 15;
  const u16* ap = W + (size_t)(o0 + w*16 + lo)*CC + hi*8;
  f32x4 acc[4] = {};
  for (int kc = 0; kc < 8; ++kc) {
    s16x8 a = *(const s16x8*)(ap + kc*32);
#pragma unroll
    for (int j = 0; j < 4; ++j) {
      s16x8 bb = *(const s16x8*)(X + ((size_t)b*NN + m0 + j*16 + lo)*CC + kc*32 + hi*8);
      acc[j] = __builtin_amdgcn_mfma_f32_16x16x32_bf16(a, bb, acc[j], 0, 0, 0);
    }
  }
#pragma unroll
  for (int j = 0; j < 4; ++j) {
#pragma unroll
    for (int r = 0; r < 4; ++r) {
      int oc = o0 + w*16 + hi*4 + r;
      int m = m0 + j*16 + lo;
      Ycm[((size_t)b*CC + oc)*NN + m] = f2bf(acc[j][r] + bias[oc]);
    }
  }
}

// -------- proj GEMM + bias + fp32 residual -> out[b][o][n] --------
__global__ __launch_bounds__(256) void gemm_cm_proj_kernel(
    const u16* __restrict__ X, const u16* __restrict__ W,
    const float* __restrict__ bias, float* __restrict__ out,
    const float* __restrict__ resid) {
  int b = blockIdx.z, m0 = blockIdx.x * 64, o0 = blockIdx.y * 64;
  int lane = threadIdx.x & 63, w = threadIdx.x >> 6;
  int hi = lane >> 4, lo = lane & 15;
  const u16* ap = W + (size_t)(o0 + w*16 + lo)*CC + hi*8;
  f32x4 acc[4] = {};
  for (int kc = 0; kc < 8; ++kc) {
    s16x8 a = *(const s16x8*)(ap + kc*32);
#pragma unroll
    for (int j = 0; j < 4; ++j) {
      s16x8 bb = *(const s16x8*)(X + ((size_t)b*NN + m0 + j*16 + lo)*CC + kc*32 + hi*8);
      acc[j] = __builtin_amdgcn_mfma_f32_16x16x32_bf16(a, bb, acc[j], 0, 0, 0);
    }
  }
#pragma unroll
  for (int j = 0; j < 4; ++j) {
#pragma unroll
    for (int r = 0; r < 4; ++r) {
      int oc = o0 + w*16 + hi*4 + r;
      int m = m0 + j*16 + lo;
      size_t idx = ((size_t)b*CC + oc)*NN + m;
      out[idx] = acc[j][r] + bias[oc] + resid[idx];
    }
  }
}

// -------- flash attention: Q[b][n][c], K[b][m][c], V[b][c][m] -> O[b][n][c] --------
__global__ __launch_bounds__(256) void flash_kernel(
    const u16* __restrict__ Q, const u16* __restrict__ K,
    const u16* __restrict__ V, u16* __restrict__ O) {
  extern __shared__ char smem[];
  char* Kl = smem;              // 2 x 32KB [64 m][256 c] bf16, swizzled
  char* Vl = smem + 65536;      // 2 x 32KB [256 c][64 m] bf16, swizzled
  char* Pl = smem + 131072;     // 4 waves x 2KB [16 q][64 m] bf16, swizzled
  const int b = blockIdx.y;
  const int q0 = blockIdx.x * 64;
  const int lane = threadIdx.x & 63;
  const int w = threadIdx.x >> 6;
  const int hi = lane >> 4, lo = lane & 15;

  s16x8 qf[8];
  {
    const u16* qp = Q + ((size_t)b*NN + q0 + w*16 + lo)*CC + hi*8;
#pragma unroll
    for (int kc = 0; kc < 8; ++kc) qf[kc] = *(const s16x8*)(qp + kc*32);
  }
  f32x4 oacc[16];
#pragma unroll
  for (int i = 0; i < 16; ++i) oacc[i] = (f32x4)0.0f;
  float M[4] = {-1e30f, -1e30f, -1e30f, -1e30f};
  float L[4] = {0.f, 0.f, 0.f, 0.f};

  const char* kbase = (const char*)(K + (size_t)b*NN*CC);
  const char* vbase = (const char*)(V + (size_t)b*CC*NN);
  char* pw = Pl + w*2048;

  auto stage = [&](int buf, int m0) {
    const char* kb = kbase + (size_t)m0 * 512;
    char* kl = Kl + buf*32768;
    char* vl = Vl + buf*32768;
#pragma unroll
    for (int p = 0; p < 8; ++p) {  // K tile: rows m (512B), swizzle source
      int off = p*4096 + w*1024 + lane*16;
      int mrow = off >> 9, cb = off & 511;
      async16(kb + (mrow << 9) + (cb ^ ((mrow & 7) << 4)), kl + p*4096 + w*1024);
    }
#pragma unroll
    for (int p = 0; p < 8; ++p) {  // V tile: rows c (128B), swizzle source
      int off = p*4096 + w*1024 + lane*16;
      int c = off >> 7, cb = off & 127;
      async16(vbase + (size_t)c*8192 + m0*2 + (cb ^ ((c & 7) << 4)),
              vl + p*4096 + w*1024);
    }
  };

  stage(0, 0);
  for (int t = 0; t < 64; ++t) {
    asm volatile("s_waitcnt vmcnt(0)" ::: "memory");
    __syncthreads();
    if (t < 63) stage((t + 1) & 1, (t + 1) * 64);
    const char* kl = Kl + (t & 1) * 32768;
    const char* vl = Vl + (t & 1) * 32768;

    // S = Q K^T (per wave: 16 q rows x 64 m)
    f32x4 s[4];
#pragma unroll
    for (int j = 0; j < 4; ++j) s[j] = (f32x4)0.0f;
#pragma unroll
    for (int kc = 0; kc < 8; ++kc) {
#pragma unroll
      for (int j = 0; j < 4; ++j) {
        const int mrow = j*16 + lo;
        const int cb = kc*64 + hi*16;
        s16x8 kf = *(const s16x8*)(kl + mrow*512 + (cb ^ ((mrow & 7) << 4)));
        s[j] = __builtin_amdgcn_mfma_f32_16x16x32_bf16(qf[kc], kf, s[j], 0, 0, 0);
      }
    }
    // online softmax (row = hi*4+r, cols across lanes 0..15 x 4 frags)
#pragma unroll
    for (int j = 0; j < 4; ++j) s[j] *= 0.0625f;  // 1/sqrt(256)
#pragma unroll
    for (int r = 0; r < 4; ++r) {
      float mx = fmaxf(fmaxf(s[0][r], s[1][r]), fmaxf(s[2][r], s[3][r]));
      mx = fmaxf(mx, __shfl_xor(mx, 1, 64));
      mx = fmaxf(mx, __shfl_xor(mx, 2, 64));
      mx = fmaxf(mx, __shfl_xor(mx, 4, 64));
      mx = fmaxf(mx, __shfl_xor(mx, 8, 64));
      float newM = fmaxf(M[r], mx);
      float alpha = exp2f((M[r] - newM) * 1.44269504f);
      M[r] = newM;
      float rs = 0.f;
#pragma unroll
      for (int j = 0; j < 4; ++j) {
        float p = exp2f((s[j][r] - newM) * 1.44269504f);
        s[j][r] = p;
        rs += p;
      }
      rs += __shfl_xor(rs, 1, 64); rs += __shfl_xor(rs, 2, 64);
      rs += __shfl_xor(rs, 4, 64); rs += __shfl_xor(rs, 8, 64);
      L[r] = L[r] * alpha + rs;
#pragma unroll
      for (int cf = 0; cf < 16; ++cf) oacc[cf][r] *= alpha;
    }
    // P -> LDS (bf16, swizzled), then reuse as A-fragments
#pragma unroll
    for (int j = 0; j < 4; ++j) {
#pragma unroll
      for (int r = 0; r < 4; ++r) {
        int row = hi*4 + r;
        int colb = (j*16 + lo) * 2;
        *(u16*)(pw + row*128 + (colb ^ ((row & 7) << 4))) = f2bf(s[j][r]);
      }
    }
    asm volatile("s_waitcnt lgkmcnt(0)" ::: "memory");
    // O += P · V
#pragma unroll
    for (int mc = 0; mc < 2; ++mc) {
      const int prow = lo;
      const int pcb = mc*64 + hi*16;
      s16x8 pf = *(const s16x8*)(pw + prow*128 + (pcb ^ ((prow & 7) << 4)));
#pragma unroll
      for (int cf = 0; cf < 16; ++cf) {
        const int c = cf*16 + lo;
        const int mb = mc*64 + hi*16;
        s16x8 vf = *(const s16x8*)(vl + c*128 + (mb ^ ((c & 7) << 4)));
        oacc[cf] = __builtin_amdgcn_mfma_f32_16x16x32_bf16(pf, vf, oacc[cf], 0, 0, 0);
      }
    }
  }
  // epilogue: O[n][c] = oacc / L
  float inv[4];
#pragma unroll
  for (int r = 0; r < 4; ++r) inv[r] = 1.0f / L[r];
#pragma unroll
  for (int cf = 0; cf < 16; ++cf) {
    int c = cf*16 + lo;
#pragma unroll
    for (int r = 0; r < 4; ++r) {
      int nn = q0 + w*16 + hi*4 + r;
      O[((size_t)b*NN + nn)*CC + c] = f2bf(oacc[cf][r] * inv[r]);
    }
  }
}

extern "C" void kernel_launch(void* const* d_in, const int* in_sizes, int n_in,
                              void* d_out, int out_size, void* d_ws, size_t ws_size,
                              hipStream_t stream) {
  const float* x  = (const float*)d_in[0];
  const float* gg = (const float*)d_in[1];
  const float* gb = (const float*)d_in[2];
  const float* wq = (const float*)d_in[3];
  const float* bq = (const float*)d_in[4];
  const float* wk = (const float*)d_in[5];
  const float* bk = (const float*)d_in[6];
  const float* wv = (const float*)d_in[7];
  const float* bv = (const float*)d_in[8];
  const float* wp = (const float*)d_in[9];
  const float* bp = (const float*)d_in[10];
  float* out = (float*)d_out;

  char* ws = (char*)d_ws;
  const size_t MATS = (size_t)BB * NN * CC;  // 4M elements
  u16* wbf  = (u16*)ws;                              // 512 KB (4 x 256x256 bf16)
  u16* xn   = (u16*)(ws + (512 << 10));              // 8 MB token-major GN out
  u16* Qtm  = xn + MATS;                             // 8 MB
  u16* Ktm  = Qtm + MATS;                            // 8 MB
  u16* Vcm  = Ktm + MATS;                            // 8 MB
  u16* Otm  = xn;                                    // reuse xn (dead after V GEMM)
  float* stats = (float*)(Vcm + MATS);               // 64 floats

  wcvt_kernel<<<dim3(64, 4), 256, 0, stream>>>(wq, wk, wv, wp, wbf);
  gn_stats_kernel<<<32, 256, 0, stream>>>(x, stats);
  gn_apply_kernel<<<dim3(64, 4), 256, 0, stream>>>(x, stats, gg, gb, xn);
  gemm_tm_kernel<<<dim3(64, 4, 4), 256, 0, stream>>>(xn, wbf + 0*65536, bq, Qtm);
  gemm_tm_kernel<<<dim3(64, 4, 4), 256, 0, stream>>>(xn, wbf + 1*65536, bk, Ktm);
  gemm_cm_bf16_kernel<<<dim3(64, 4, 4), 256, 0, stream>>>(xn, wbf + 2*65536, bv, Vcm);
  hipFuncSetAttribute((const void*)flash_kernel,
                      hipFuncAttributeMaxDynamicSharedMemorySize, 139264);
  flash_kernel<<<dim3(64, 4), 256, 139264, stream>>>(Qtm, Ktm, Vcm, Otm);
  gemm_cm_proj_kernel<<<dim3(64, 4, 4), 256, 0, stream>>>(Otm, wbf + 3*65536, bp, out, x);
}

// Round 2
// 220.642 us; speedup vs baseline: 1.6025x; 1.6025x over previous
//
#include <hip/hip_runtime.h>
#include <stdint.h>

#define BB 4
#define CC 256
#define NN 4096
#define GG 8

typedef unsigned short u16;
typedef __attribute__((ext_vector_type(4))) float f32x4;
typedef __attribute__((ext_vector_type(8))) short s16x8;
typedef __attribute__((ext_vector_type(4))) u16 u16x4;
typedef __attribute__((ext_vector_type(8))) u16 u16x8;

__device__ __forceinline__ u16 f2bf(float f) {
  union { float f; uint32_t u; } v; v.f = f;
  return (u16)((v.u + 0x7FFFu + ((v.u >> 16) & 1u)) >> 16);
}

__device__ __forceinline__ void async16(const void* g, void* l) {
  __builtin_amdgcn_global_load_lds(
      (const __attribute__((address_space(1))) void*)g,
      (__attribute__((address_space(3))) void*)l, 16, 0, 0);
}

// ---------------- weight f32 -> bf16 ----------------
__global__ __launch_bounds__(256) void wcvt_kernel(
    const float* __restrict__ w0, const float* __restrict__ w1,
    const float* __restrict__ w2, const float* __restrict__ w3,
    u16* __restrict__ dst) {
  const float* src = (blockIdx.y == 0) ? w0 : (blockIdx.y == 1) ? w1
                   : (blockIdx.y == 2) ? w2 : w3;
  int i = blockIdx.x * 256 + threadIdx.x;
  f32x4 v = ((const f32x4*)src)[i];
  u16x4 o;
  o[0] = f2bf(v[0]); o[1] = f2bf(v[1]); o[2] = f2bf(v[2]); o[3] = f2bf(v[3]);
  ((u16x4*)(dst + (size_t)blockIdx.y * 65536))[i] = o;
}

// ---------------- GroupNorm partial sums: 256 blocks ----------------
__global__ __launch_bounds__(256) void gn_part_kernel(
    const float* __restrict__ x, float* __restrict__ part) {
  int bg = blockIdx.x, seg = blockIdx.y;  // 32 x 8
  const f32x4* xp = (const f32x4*)(x + (size_t)bg * 131072 + seg * 16384);
  float s = 0.f, ss = 0.f;
  for (int i = threadIdx.x; i < 4096; i += 256) {
    f32x4 v = xp[i];
    s += v[0] + v[1] + v[2] + v[3];
    ss += v[0]*v[0] + v[1]*v[1] + v[2]*v[2] + v[3]*v[3];
  }
  for (int d = 1; d < 64; d <<= 1) {
    s += __shfl_xor(s, d, 64);
    ss += __shfl_xor(ss, d, 64);
  }
  __shared__ float red[8];
  int w = threadIdx.x >> 6, lane = threadIdx.x & 63;
  if (lane == 0) { red[w*2] = s; red[w*2+1] = ss; }
  __syncthreads();
  if (threadIdx.x == 0) {
    part[(bg*8 + seg)*2]     = red[0]+red[2]+red[4]+red[6];
    part[(bg*8 + seg)*2 + 1] = red[1]+red[3]+red[5]+red[7];
  }
}

// -------- GN apply (+final stat reduce) + transpose to xn[b][n][c] --------
__global__ __launch_bounds__(256) void gn_apply_kernel(
    const float* __restrict__ x, const float* __restrict__ part,
    const float* __restrict__ gamma, const float* __restrict__ beta,
    u16* __restrict__ xn) {
  int b = blockIdx.y, n0 = blockIdx.x * 64, t = threadIdx.x;
  __shared__ float gstat[16];  // 8 groups x (mean, rstd)
  __shared__ u16 tile[16384];  // [256 c][64 n] bf16, XOR-swizzled
  if (t < 8) {
    float S = 0.f, SS = 0.f;
    for (int seg = 0; seg < 8; ++seg) {
      S  += part[((b*8 + t)*8 + seg)*2];
      SS += part[((b*8 + t)*8 + seg)*2 + 1];
    }
    float mean = S * (1.0f/131072.0f);
    float var = SS * (1.0f/131072.0f) - mean*mean;
    gstat[t*2] = mean;
    gstat[t*2+1] = rsqrtf(var + 1e-5f);
  }
  __syncthreads();
  for (int p = 0; p < 16; ++p) {
    int c = p*16 + (t >> 4);
    int n4 = (t & 15) * 4;
    f32x4 v = *(const f32x4*)(x + ((size_t)b*CC + c)*NN + n0 + n4);
    float mean = gstat[(c>>5)*2], rstd = gstat[(c>>5)*2+1];
    float ga = gamma[c] * rstd;
    float be = beta[c] - mean * ga;
    u16x4 o;
    o[0]=f2bf(v[0]*ga+be); o[1]=f2bf(v[1]*ga+be);
    o[2]=f2bf(v[2]*ga+be); o[3]=f2bf(v[3]*ga+be);
    int swz = (((c & 7) ^ ((c >> 3) & 7)) << 4);
    *(u16x4*)((char*)tile + c*128 + ((n4*2) ^ swz)) = o;
  }
  __syncthreads();
  for (int p = 0; p < 8; ++p) {
    int n = p*8 + (t >> 5);
    int c0 = (t & 31) * 8;
    u16x8 o;
#pragma unroll
    for (int j = 0; j < 8; ++j) {
      int c = c0 + j;
      int swz = (((c & 7) ^ ((c >> 3) & 7)) << 4);
      o[j] = *(const u16*)((const char*)tile + c*128 + ((n*2) ^ swz));
    }
    *(u16x8*)(xn + ((size_t)b*NN + n0 + n)*CC + c0) = o;
  }
}

// -------- GEMM token-major out: Y[b][n][o] --------
__global__ __launch_bounds__(256) void gemm_tm_kernel(
    const u16* __restrict__ X, const u16* __restrict__ W,
    const float* __restrict__ bias, u16* __restrict__ Y) {
  int b = blockIdx.z, n0 = blockIdx.x * 64, o0 = blockIdx.y * 64;
  int lane = threadIdx.x & 63, w = threadIdx.x >> 6;
  int hi = lane >> 4, lo = lane & 15;
  const u16* xp = X + ((size_t)b*NN + n0 + w*16 + lo)*CC + hi*8;
  f32x4 acc[4] = {};
  for (int kc = 0; kc < 8; ++kc) {
    s16x8 a = *(const s16x8*)(xp + kc*32);
#pragma unroll
    for (int j = 0; j < 4; ++j) {
      s16x8 bb = *(const s16x8*)(W + (size_t)(o0 + j*16 + lo)*CC + kc*32 + hi*8);
      acc[j] = __builtin_amdgcn_mfma_f32_16x16x32_bf16(a, bb, acc[j], 0, 0, 0);
    }
  }
#pragma unroll
  for (int j = 0; j < 4; ++j) {
    int oc = o0 + j*16 + lo;
    float bv = bias[oc];
#pragma unroll
    for (int r = 0; r < 4; ++r) {
      int nn = n0 + w*16 + hi*4 + r;
      Y[((size_t)b*NN + nn)*CC + oc] = f2bf(acc[j][r] + bv);
    }
  }
}

// -------- GEMM channel-major out: Y[b][o][m] --------
__global__ __launch_bounds__(256) void gemm_cm_bf16_kernel(
    const u16* __restrict__ X, const u16* __restrict__ W,
    const float* __restrict__ bias, u16* __restrict__ Ycm) {
  int b = blockIdx.z, m0 = blockIdx.x * 64, o0 = blockIdx.y * 64;
  int lane = threadIdx.x & 63, w = threadIdx.x >> 6;
  int hi = lane >> 4, lo = lane & 15;
  const u16* ap = W + (size_t)(o0 + w*16 + lo)*CC + hi*8;
  f32x4 acc[4] = {};
  for (int kc = 0; kc < 8; ++kc) {
    s16x8 a = *(const s16x8*)(ap + kc*32);
#pragma unroll
    for (int j = 0; j < 4; ++j) {
      s16x8 bb = *(const s16x8*)(X + ((size_t)b*NN + m0 + j*16 + lo)*CC + kc*32 + hi*8);
      acc[j] = __builtin_amdgcn_mfma_f32_16x16x32_bf16(a, bb, acc[j], 0, 0, 0);
    }
  }
#pragma unroll
  for (int j = 0; j < 4; ++j) {
#pragma unroll
    for (int r = 0; r < 4; ++r) {
      int oc = o0 + w*16 + hi*4 + r;
      int m = m0 + j*16 + lo;
      Ycm[((size_t)b*CC + oc)*NN + m] = f2bf(acc[j][r] + bias[oc]);
    }
  }
}

// -------- proj GEMM + bias + fp32 residual --------
__global__ __launch_bounds__(256) void gemm_cm_proj_kernel(
    const u16* __restrict__ X, const u16* __restrict__ W,
    const float* __restrict__ bias, float* __restrict__ out,
    const float* __restrict__ resid) {
  int b = blockIdx.z, m0 = blockIdx.x * 64, o0 = blockIdx.y * 64;
  int lane = threadIdx.x & 63, w = threadIdx.x >> 6;
  int hi = lane >> 4, lo = lane & 15;
  const u16* ap = W + (size_t)(o0 + w*16 + lo)*CC + hi*8;
  f32x4 acc[4] = {};
  for (int kc = 0; kc < 8; ++kc) {
    s16x8 a = *(const s16x8*)(ap + kc*32);
#pragma unroll
    for (int j = 0; j < 4; ++j) {
      s16x8 bb = *(const s16x8*)(X + ((size_t)b*NN + m0 + j*16 + lo)*CC + kc*32 + hi*8);
      acc[j] = __builtin_amdgcn_mfma_f32_16x16x32_bf16(a, bb, acc[j], 0, 0, 0);
    }
  }
#pragma unroll
  for (int j = 0; j < 4; ++j) {
#pragma unroll
    for (int r = 0; r < 4; ++r) {
      int oc = o0 + w*16 + hi*4 + r;
      int m = m0 + j*16 + lo;
      size_t idx = ((size_t)b*CC + oc)*NN + m;
      out[idx] = acc[j][r] + bias[oc] + resid[idx];
    }
  }
}

// -------- flash attention, M-free softmax, 8 waves / 2 m-groups --------
// Q[b][n][c], K[b][m][c], V[b][c][m] -> O[b][n][c]
__global__ __launch_bounds__(512, 2) void flash_kernel(
    const u16* __restrict__ Q, const u16* __restrict__ K,
    const u16* __restrict__ V, u16* __restrict__ O) {
  extern __shared__ char smem[];
  // group g: K dbuf at g*65536 (2x16KB), V dbuf at g*65536+32768 (2x16KB)
  // P: 131072 + w*1024 (8 waves x 1KB)
  const int bid = blockIdx.x;
  const int xcd = bid & 7;
  const int widx = bid >> 3;            // 0..31
  const int b = xcd & 3;                // one batch per XCD
  const int q0 = (((xcd >> 2) * 32) + widx) * 64;
  const int tid = threadIdx.x;
  const int lane = tid & 63;
  const int w = tid >> 6;               // 0..7
  const int g = w >> 2;                 // m-group
  const int wq = w & 3;                 // q-subtile
  const int hi = lane >> 4, lo = lane & 15;
  const int tg = tid & 255;             // thread-in-group

  char* Kg = smem + g * 65536;
  char* Vg = smem + g * 65536 + 32768;
  char* pw = smem + 131072 + w * 1024;

  s16x8 qf[8];
  {
    const u16* qp = Q + ((size_t)b*NN + q0 + wq*16 + lo)*CC + hi*8;
#pragma unroll
    for (int kc = 0; kc < 8; ++kc) qf[kc] = *(const s16x8*)(qp + kc*32);
  }
  f32x4 oacc[16];
#pragma unroll
  for (int i = 0; i < 16; ++i) oacc[i] = (f32x4)0.0f;
  float Lp[4] = {0.f, 0.f, 0.f, 0.f};

  const char* kbase = (const char*)(K + (size_t)b*NN*CC);
  const char* vbase = (const char*)(V + (size_t)b*CC*NN);

  auto stage = [&](int buf, int m0) {
    char* kl = Kg + buf*16384;
    char* vl = Vg + buf*16384;
#pragma unroll
    for (int p = 0; p < 4; ++p) {  // K: 32 rows x 512B
      int off = p*4096 + tg*16;
      int mrow = off >> 9, cb = off & 511;
      async16(kbase + (size_t)m0*512 + (size_t)mrow*512 + (cb ^ ((mrow & 7) << 4)),
              kl + off);
    }
#pragma unroll
    for (int p = 0; p < 4; ++p) {  // V: 256 rows x 64B
      int off = p*4096 + tg*16;
      int c = off >> 6, cb = off & 63;
      async16(vbase + (size_t)c*8192 + (size_t)m0*2 + (cb ^ ((c & 3) << 4)),
              vl + off);
    }
  };

  stage(0, g * 32);
  for (int t = 0; t < 64; ++t) {
    asm volatile("s_waitcnt vmcnt(0)" ::: "memory");
    __syncthreads();
    if (t < 63) stage((t + 1) & 1, (2*(t+1) + g) * 32);
    const char* kl = Kg + (t & 1) * 16384;
    const char* vl = Vg + (t & 1) * 16384;

    // S = Q K^T : 16 q rows x 32 m
    f32x4 s[2];
    s[0] = (f32x4)0.0f; s[1] = (f32x4)0.0f;
    __builtin_amdgcn_s_setprio(1);
#pragma unroll
    for (int kc = 0; kc < 8; ++kc) {
#pragma unroll
      for (int j = 0; j < 2; ++j) {
        const int mrow = j*16 + lo;
        const int cb = kc*64 + hi*16;
        s16x8 kf = *(const s16x8*)(kl + mrow*512 + (cb ^ ((mrow & 7) << 4)));
        s[j] = __builtin_amdgcn_mfma_f32_16x16x32_bf16(qf[kc], kf, s[j], 0, 0, 0);
      }
    }
    __builtin_amdgcn_s_setprio(0);

    // P = exp(S/16), per-lane partial L, P -> LDS bf16
#pragma unroll
    for (int j = 0; j < 2; ++j) {
#pragma unroll
      for (int r = 0; r < 4; ++r) {
        float p = exp2f(s[j][r] * 0.09016844f);  // log2(e)/16
        s[j][r] = p;
        Lp[r] += p;
        int row = hi*4 + r;
        int colb = (j*16 + lo) * 2;
        int swz = (((row & 3) ^ ((row >> 2) & 3)) << 4);
        *(u16*)(pw + row*64 + (colb ^ swz)) = f2bf(p);
      }
    }

    // O += P V : P[16 x 32] . V[32 x 256]
    const int pswz = (((lo & 3) ^ ((lo >> 2) & 3)) << 4);
    s16x8 pf = *(const s16x8*)(pw + lo*64 + ((hi*16) ^ pswz));
    __builtin_amdgcn_s_setprio(1);
#pragma unroll
    for (int cf = 0; cf < 16; ++cf) {
      const int c = cf*16 + lo;
      s16x8 vf = *(const s16x8*)(vl + c*64 + ((hi*16) ^ ((c & 3) << 4)));
      oacc[cf] = __builtin_amdgcn_mfma_f32_16x16x32_bf16(pf, vf, oacc[cf], 0, 0, 0);
    }
    __builtin_amdgcn_s_setprio(0);
  }

  // merge group 1 partials into group 0 via LDS
  __syncthreads();
  if (g == 1) {
    float* ob = (float*)smem + (wq*64 + lane) * 64;
#pragma unroll
    for (int i = 0; i < 16; ++i) *(f32x4*)(ob + i*4) = oacc[i];
    float* lb = (float*)(smem + 65536) + (wq*64 + lane)*4;
#pragma unroll
    for (int r = 0; r < 4; ++r) lb[r] = Lp[r];
  }
  __syncthreads();
  if (g == 0) {
    const float* ob = (const float*)smem + (wq*64 + lane) * 64;
#pragma unroll
    for (int i = 0; i < 16; ++i) oacc[i] += *(const f32x4*)(ob + i*4);
    const float* lb = (const float*)(smem + 65536) + (wq*64 + lane)*4;
    float inv[4];
#pragma unroll
    for (int r = 0; r < 4; ++r) {
      float L = Lp[r] + lb[r];
      L += __shfl_xor(L, 1, 64); L += __shfl_xor(L, 2, 64);
      L += __shfl_xor(L, 4, 64); L += __shfl_xor(L, 8, 64);
      inv[r] = 1.0f / L;
    }
#pragma unroll
    for (int cf = 0; cf < 16; ++cf) {
      int c = cf*16 + lo;
#pragma unroll
      for (int r = 0; r < 4; ++r) {
        int nn = q0 + wq*16 + hi*4 + r;
        O[((size_t)b*NN + nn)*CC + c] = f2bf(oacc[cf][r] * inv[r]);
      }
    }
  }
}

extern "C" void kernel_launch(void* const* d_in, const int* in_sizes, int n_in,
                              void* d_out, int out_size, void* d_ws, size_t ws_size,
                              hipStream_t stream) {
  const float* x  = (const float*)d_in[0];
  const float* gg = (const float*)d_in[1];
  const float* gb = (const float*)d_in[2];
  const float* wq = (const float*)d_in[3];
  const float* bq = (const float*)d_in[4];
  const float* wk = (const float*)d_in[5];
  const float* bk = (const float*)d_in[6];
  const float* wv = (const float*)d_in[7];
  const float* bv = (const float*)d_in[8];
  const float* wp = (const float*)d_in[9];
  const float* bp = (const float*)d_in[10];
  float* out = (float*)d_out;

  char* ws = (char*)d_ws;
  const size_t MATS = (size_t)BB * NN * CC;
  u16* wbf  = (u16*)ws;                 // 512 KB
  u16* xn   = (u16*)(ws + (512 << 10)); // 8 MB
  u16* Qtm  = xn + MATS;
  u16* Ktm  = Qtm + MATS;
  u16* Vcm  = Ktm + MATS;
  u16* Otm  = xn;                       // reuse (xn dead after V GEMM)
  float* part = (float*)(Vcm + MATS);   // 512 floats

  wcvt_kernel<<<dim3(64, 4), 256, 0, stream>>>(wq, wk, wv, wp, wbf);
  gn_part_kernel<<<dim3(32, 8), 256, 0, stream>>>(x, part);
  gn_apply_kernel<<<dim3(64, 4), 256, 0, stream>>>(x, part, gg, gb, xn);
  gemm_tm_kernel<<<dim3(64, 4, 4), 256, 0, stream>>>(xn, wbf + 0*65536, bq, Qtm);
  gemm_tm_kernel<<<dim3(64, 4, 4), 256, 0, stream>>>(xn, wbf + 1*65536, bk, Ktm);
  gemm_cm_bf16_kernel<<<dim3(64, 4, 4), 256, 0, stream>>>(xn, wbf + 2*65536, bv, Vcm);
  hipFuncSetAttribute((const void*)flash_kernel,
                      hipFuncAttributeMaxDynamicSharedMemorySize, 139264);
  flash_kernel<<<256, 512, 139264, stream>>>(Qtm, Ktm, Vcm, Otm);
  gemm_cm_proj_kernel<<<dim3(64, 4, 4), 256, 0, stream>>>(Otm, wbf + 3*65536, bp, out, x);
}

// Round 3
// 203.176 us; speedup vs baseline: 1.7403x; 1.0860x over previous
//
#include <hip/hip_runtime.h>
#include <stdint.h>

#define BB 4
#define CC 256
#define NN 4096
#define GG 8

typedef unsigned short u16;
typedef __attribute__((ext_vector_type(4))) float f32x4;
typedef __attribute__((ext_vector_type(16))) float f32x16;
typedef __attribute__((ext_vector_type(8))) short s16x8;
typedef __attribute__((ext_vector_type(4))) u16 u16x4;
typedef __attribute__((ext_vector_type(8))) u16 u16x8;

__device__ __forceinline__ u16 f2bf(float f) {
  union { float f; uint32_t u; } v; v.f = f;
  return (u16)((v.u + 0x7FFFu + ((v.u >> 16) & 1u)) >> 16);
}
__device__ __forceinline__ float bf2f(uint32_t u) {
  union { uint32_t u; float f; } v; v.u = u << 16;
  return v.f;
}

__device__ __forceinline__ void async16(const void* g, void* l) {
  __builtin_amdgcn_global_load_lds(
      (const __attribute__((address_space(1))) void*)g,
      (__attribute__((address_space(3))) void*)l, 16, 0, 0);
}

// ---------------- weight f32 -> bf16 ----------------
__global__ __launch_bounds__(256) void wcvt_kernel(
    const float* __restrict__ w0, const float* __restrict__ w1,
    const float* __restrict__ w2, const float* __restrict__ w3,
    u16* __restrict__ dst) {
  const float* src = (blockIdx.y == 0) ? w0 : (blockIdx.y == 1) ? w1
                   : (blockIdx.y == 2) ? w2 : w3;
  int i = blockIdx.x * 256 + threadIdx.x;
  f32x4 v = ((const f32x4*)src)[i];
  u16x4 o;
  o[0] = f2bf(v[0]); o[1] = f2bf(v[1]); o[2] = f2bf(v[2]); o[3] = f2bf(v[3]);
  ((u16x4*)(dst + (size_t)blockIdx.y * 65536))[i] = o;
}

// ---------------- GroupNorm partial sums: 256 blocks ----------------
__global__ __launch_bounds__(256) void gn_part_kernel(
    const float* __restrict__ x, float* __restrict__ part) {
  int bg = blockIdx.x, seg = blockIdx.y;  // 32 x 8
  const f32x4* xp = (const f32x4*)(x + (size_t)bg * 131072 + seg * 16384);
  float s = 0.f, ss = 0.f;
  for (int i = threadIdx.x; i < 4096; i += 256) {
    f32x4 v = xp[i];
    s += v[0] + v[1] + v[2] + v[3];
    ss += v[0]*v[0] + v[1]*v[1] + v[2]*v[2] + v[3]*v[3];
  }
  for (int d = 1; d < 64; d <<= 1) {
    s += __shfl_xor(s, d, 64);
    ss += __shfl_xor(ss, d, 64);
  }
  __shared__ float red[8];
  int w = threadIdx.x >> 6, lane = threadIdx.x & 63;
  if (lane == 0) { red[w*2] = s; red[w*2+1] = ss; }
  __syncthreads();
  if (threadIdx.x == 0) {
    part[(bg*8 + seg)*2]     = red[0]+red[2]+red[4]+red[6];
    part[(bg*8 + seg)*2 + 1] = red[1]+red[3]+red[5]+red[7];
  }
}

// -------- GN apply (+final stat reduce) + transpose to xn[b][n][c] --------
__global__ __launch_bounds__(256) void gn_apply_kernel(
    const float* __restrict__ x, const float* __restrict__ part,
    const float* __restrict__ gamma, const float* __restrict__ beta,
    u16* __restrict__ xn) {
  int b = blockIdx.y, n0 = blockIdx.x * 64, t = threadIdx.x;
  __shared__ float gstat[16];
  __shared__ u16 tile[16384];  // [256 c][64 n] bf16, XOR-swizzled
  if (t < 8) {
    float S = 0.f, SS = 0.f;
    for (int seg = 0; seg < 8; ++seg) {
      S  += part[((b*8 + t)*8 + seg)*2];
      SS += part[((b*8 + t)*8 + seg)*2 + 1];
    }
    float mean = S * (1.0f/131072.0f);
    float var = SS * (1.0f/131072.0f) - mean*mean;
    gstat[t*2] = mean;
    gstat[t*2+1] = rsqrtf(var + 1e-5f);
  }
  __syncthreads();
  for (int p = 0; p < 16; ++p) {
    int c = p*16 + (t >> 4);
    int n4 = (t & 15) * 4;
    f32x4 v = *(const f32x4*)(x + ((size_t)b*CC + c)*NN + n0 + n4);
    float mean = gstat[(c>>5)*2], rstd = gstat[(c>>5)*2+1];
    float ga = gamma[c] * rstd;
    float be = beta[c] - mean * ga;
    u16x4 o;
    o[0]=f2bf(v[0]*ga+be); o[1]=f2bf(v[1]*ga+be);
    o[2]=f2bf(v[2]*ga+be); o[3]=f2bf(v[3]*ga+be);
    int swz = (((c & 7) ^ ((c >> 3) & 7)) << 4);
    *(u16x4*)((char*)tile + c*128 + ((n4*2) ^ swz)) = o;
  }
  __syncthreads();
  for (int p = 0; p < 8; ++p) {
    int n = p*8 + (t >> 5);
    int c0 = (t & 31) * 8;
    u16x8 o;
#pragma unroll
    for (int j = 0; j < 8; ++j) {
      int c = c0 + j;
      int swz = (((c & 7) ^ ((c >> 3) & 7)) << 4);
      o[j] = *(const u16*)((const char*)tile + c*128 + ((n*2) ^ swz));
    }
    *(u16x8*)(xn + ((size_t)b*NN + n0 + n)*CC + c0) = o;
  }
}

// -------- GEMM token-major out: Y[b][n][o] --------
__global__ __launch_bounds__(256) void gemm_tm_kernel(
    const u16* __restrict__ X, const u16* __restrict__ W,
    const float* __restrict__ bias, u16* __restrict__ Y) {
  int b = blockIdx.z, n0 = blockIdx.x * 64, o0 = blockIdx.y * 64;
  int lane = threadIdx.x & 63, w = threadIdx.x >> 6;
  int hi = lane >> 4, lo = lane & 15;
  const u16* xp = X + ((size_t)b*NN + n0 + w*16 + lo)*CC + hi*8;
  f32x4 acc[4] = {};
  for (int kc = 0; kc < 8; ++kc) {
    s16x8 a = *(const s16x8*)(xp + kc*32);
#pragma unroll
    for (int j = 0; j < 4; ++j) {
      s16x8 bb = *(const s16x8*)(W + (size_t)(o0 + j*16 + lo)*CC + kc*32 + hi*8);
      acc[j] = __builtin_amdgcn_mfma_f32_16x16x32_bf16(a, bb, acc[j], 0, 0, 0);
    }
  }
#pragma unroll
  for (int j = 0; j < 4; ++j) {
    int oc = o0 + j*16 + lo;
    float bv = bias[oc];
#pragma unroll
    for (int r = 0; r < 4; ++r) {
      int nn = n0 + w*16 + hi*4 + r;
      Y[((size_t)b*NN + nn)*CC + oc] = f2bf(acc[j][r] + bv);
    }
  }
}

// -------- GEMM channel-major out: Y[b][o][m] --------
__global__ __launch_bounds__(256) void gemm_cm_bf16_kernel(
    const u16* __restrict__ X, const u16* __restrict__ W,
    const float* __restrict__ bias, u16* __restrict__ Ycm) {
  int b = blockIdx.z, m0 = blockIdx.x * 64, o0 = blockIdx.y * 64;
  int lane = threadIdx.x & 63, w = threadIdx.x >> 6;
  int hi = lane >> 4, lo = lane & 15;
  const u16* ap = W + (size_t)(o0 + w*16 + lo)*CC + hi*8;
  f32x4 acc[4] = {};
  for (int kc = 0; kc < 8; ++kc) {
    s16x8 a = *(const s16x8*)(ap + kc*32);
#pragma unroll
    for (int j = 0; j < 4; ++j) {
      s16x8 bb = *(const s16x8*)(X + ((size_t)b*NN + m0 + j*16 + lo)*CC + kc*32 + hi*8);
      acc[j] = __builtin_amdgcn_mfma_f32_16x16x32_bf16(a, bb, acc[j], 0, 0, 0);
    }
  }
#pragma unroll
  for (int j = 0; j < 4; ++j) {
#pragma unroll
    for (int r = 0; r < 4; ++r) {
      int oc = o0 + w*16 + hi*4 + r;
      int m = m0 + j*16 + lo;
      Ycm[((size_t)b*CC + oc)*NN + m] = f2bf(acc[j][r] + bias[oc]);
    }
  }
}

// -------- proj GEMM + bias + fp32 residual --------
__global__ __launch_bounds__(256) void gemm_cm_proj_kernel(
    const u16* __restrict__ X, const u16* __restrict__ W,
    const float* __restrict__ bias, float* __restrict__ out,
    const float* __restrict__ resid) {
  int b = blockIdx.z, m0 = blockIdx.x * 64, o0 = blockIdx.y * 64;
  int lane = threadIdx.x & 63, w = threadIdx.x >> 6;
  int hi = lane >> 4, lo = lane & 15;
  const u16* ap = W + (size_t)(o0 + w*16 + lo)*CC + hi*8;
  f32x4 acc[4] = {};
  for (int kc = 0; kc < 8; ++kc) {
    s16x8 a = *(const s16x8*)(ap + kc*32);
#pragma unroll
    for (int j = 0; j < 4; ++j) {
      s16x8 bb = *(const s16x8*)(X + ((size_t)b*NN + m0 + j*16 + lo)*CC + kc*32 + hi*8);
      acc[j] = __builtin_amdgcn_mfma_f32_16x16x32_bf16(a, bb, acc[j], 0, 0, 0);
    }
  }
#pragma unroll
  for (int j = 0; j < 4; ++j) {
#pragma unroll
    for (int r = 0; r < 4; ++r) {
      int oc = o0 + w*16 + hi*4 + r;
      int m = m0 + j*16 + lo;
      size_t idx = ((size_t)b*CC + oc)*NN + m;
      out[idx] = acc[j][r] + bias[oc] + resid[idx];
    }
  }
}

// -------- flash attention v3: 32x32 MFMA, swapped operands, in-reg P --------
// Q[b][n][c], K[b][m][c], V[b][c][m] -> Opart (bf16-pair u32 [pb][c/2][q]), Lpart
// 512 blocks x 256 thr; block = (b, part, qb): 128 q rows, m in [part*1024, +1024)
__global__ __launch_bounds__(256, 2) void flash_kernel(
    const u16* __restrict__ Q, const u16* __restrict__ K,
    const u16* __restrict__ V, uint32_t* __restrict__ Op32,
    float* __restrict__ Lpart) {
  __shared__ char kl[32768];  // [32 cslot][64 m][16B]
  __shared__ char vl[32768];  // [8 mslot][256 c][16B]
  const int bid = blockIdx.x;
  const int b    = bid & 3;
  const int part = ((bid >> 2) & 1) | (((bid >> 8) & 1) << 1);
  const int qb   = (bid >> 3) & 31;
  const int tid = threadIdx.x;
  const int lane = tid & 63;
  const int w = tid >> 6;
  const int cl = lane & 31;
  const int h = lane >> 5;
  const int q = qb*128 + w*32 + cl;

  // Q as B-fragments: lane: col q, k = kc*16 + 8h + j
  s16x8 qreg[16];
  {
    const u16* qp = Q + ((size_t)b*NN + q)*CC + h*8;
#pragma unroll
    for (int kc = 0; kc < 16; ++kc) qreg[kc] = *(const s16x8*)(qp + kc*16);
  }
  f32x16 oacc[8];
#pragma unroll
  for (int i = 0; i < 8; ++i) oacc[i] = (f32x16)0.f;
  float Lp = 0.f;

  const char* kbase = (const char*)(K + (size_t)b*NN*CC);
  const char* vbase = (const char*)(V + (size_t)b*CC*NN);
  const int mbase = part*1024;

  // K LDS linear L = p*4096+tid*16  <->  (m=lane, cslot=p*4+w)
  auto stageK = [&](int m0) {
#pragma unroll
    for (int p = 0; p < 8; ++p)
      async16(kbase + (size_t)(m0 + lane)*512 + (p*4 + w)*16,
              kl + p*4096 + tid*16);
  };
  // V LDS linear L = p*4096+tid*16  <->  (c=tid, mslot=p)
  auto stageV = [&](int m0) {
#pragma unroll
    for (int p = 0; p < 8; ++p)
      async16(vbase + (size_t)tid*8192 + m0*2 + p*16,
              vl + p*4096 + tid*16);
  };

  stageK(mbase);
  stageV(mbase);

  const float SC = 0.0901684857f;  // log2(e)/16

  for (int it = 0; it < 16; ++it) {
    const int m0 = mbase + it*64;
    __syncthreads();  // drains own vmcnt, then barrier: tiles ready

    // S^T = K . Q^T : two 32x32 tiles (m-rows x q-cols)
    f32x16 s0 = (f32x16)0.f, s1 = (f32x16)0.f;
    __builtin_amdgcn_s_setprio(1);
#pragma unroll
    for (int kc = 0; kc < 16; ++kc) {
      s16x8 k0 = *(const s16x8*)(kl + (kc*2+h)*1024 + cl*16);
      s16x8 k1 = *(const s16x8*)(kl + (kc*2+h)*1024 + (32+cl)*16);
      s0 = __builtin_amdgcn_mfma_f32_32x32x16_bf16(k0, qreg[kc], s0, 0, 0, 0);
      s1 = __builtin_amdgcn_mfma_f32_32x32x16_bf16(k1, qreg[kc], s1, 0, 0, 0);
    }
    __builtin_amdgcn_s_setprio(0);
    __builtin_amdgcn_s_barrier();      // all waves done reading kl
    if (it < 15) stageK(m0 + 64);      // overlaps softmax + PV

    // M-free softmax + build P^T B-fragments in-register
    s16x8 pf[4];
#pragma unroll
    for (int half = 0; half < 4; ++half) {
      const f32x16& sv = (half < 2) ? s0 : s1;
      const int base = (half & 1) * 8;
      float pe[8];
#pragma unroll
      for (int j = 0; j < 8; ++j) {
        float p = exp2f(sv[base + j] * SC);
        pe[j] = p;
        Lp += p;
      }
      uint32_t a0, a1, a2, a3;
      asm("v_cvt_pk_bf16_f32 %0, %1, %2" : "=v"(a0) : "v"(pe[0]), "v"(pe[1]));
      asm("v_cvt_pk_bf16_f32 %0, %1, %2" : "=v"(a1) : "v"(pe[2]), "v"(pe[3]));
      asm("v_cvt_pk_bf16_f32 %0, %1, %2" : "=v"(a2) : "v"(pe[4]), "v"(pe[5]));
      asm("v_cvt_pk_bf16_f32 %0, %1, %2" : "=v"(a3) : "v"(pe[6]), "v"(pe[7]));
      asm("v_permlane32_swap_b32 %0, %1" : "+v"(a0), "+v"(a2));
      asm("v_permlane32_swap_b32 %0, %1" : "+v"(a1), "+v"(a3));
      union { uint32_t w[4]; s16x8 v; } u;
      u.w[0] = a0; u.w[1] = a1; u.w[2] = a2; u.w[3] = a3;
      pf[half] = u.v;
    }

    // O^T += V^T . P^T
    __builtin_amdgcn_s_setprio(1);
#pragma unroll
    for (int ks = 0; ks < 4; ++ks) {
#pragma unroll
      for (int ct = 0; ct < 8; ++ct) {
        s16x8 vf = *(const s16x8*)(vl + (ks*2+h)*4096 + (ct*32+cl)*16);
        oacc[ct] = __builtin_amdgcn_mfma_f32_32x32x16_bf16(vf, pf[ks], oacc[ct], 0, 0, 0);
      }
    }
    __builtin_amdgcn_s_setprio(0);
    __builtin_amdgcn_s_barrier();      // all waves done reading vl
    if (it < 15) stageV(m0 + 64);
  }

  // epilogue: partial L and partial O^T (bf16 pairs along c)
  float Lq = Lp + __shfl_xor(Lp, 32, 64);
  const int pb = part*4 + b;
  if (lane < 32) Lpart[(size_t)pb*NN + q] = Lq;
  const size_t basePB = (size_t)pb * 128 * NN;
#pragma unroll
  for (int ct = 0; ct < 8; ++ct) {
#pragma unroll
    for (int i2 = 0; i2 < 8; ++i2) {
      const int i = i2*2;
      float lo_ = oacc[ct][i], hi_ = oacc[ct][i+1];
      uint32_t pk;
      asm("v_cvt_pk_bf16_f32 %0, %1, %2" : "=v"(pk) : "v"(lo_), "v"(hi_));
      const int cp = ct*16 + ((i&3)>>1) + 4*(i>>2) + 2*h;  // c/2
      Op32[basePB + (size_t)cp*NN + q] = pk;
    }
  }
}

// -------- merge 4 m-partials -> Otm[b][q][c] bf16 --------
__global__ __launch_bounds__(256) void merge_kernel(
    const uint32_t* __restrict__ Op32, const float* __restrict__ Lpart,
    u16* __restrict__ Otm) {
  const int qb = blockIdx.x;   // 16 x 256 q
  const int cq = blockIdx.y;   // 4 x 64 c
  const int b  = blockIdx.z;
  const int q = qb*256 + threadIdx.x;
  float L = 0.f;
#pragma unroll
  for (int p = 0; p < 4; ++p) L += Lpart[(size_t)(p*4 + b)*NN + q];
  const float inv = 1.0f / L;
#pragma unroll
  for (int cb = 0; cb < 8; ++cb) {
    const int c0 = cq*64 + cb*8;
    float v[8] = {0.f,0.f,0.f,0.f,0.f,0.f,0.f,0.f};
#pragma unroll
    for (int p = 0; p < 4; ++p) {
      const size_t base = (size_t)(p*4 + b) * 128 * NN;
#pragma unroll
      for (int jw = 0; jw < 4; ++jw) {
        uint32_t pk = Op32[base + (size_t)(c0/2 + jw)*NN + q];
        v[jw*2]   += bf2f(pk & 0xffffu);
        v[jw*2+1] += bf2f(pk >> 16);
      }
    }
    u16x8 o;
#pragma unroll
    for (int j = 0; j < 8; ++j) o[j] = f2bf(v[j] * inv);
    *(u16x8*)(Otm + ((size_t)b*NN + q)*CC + c0) = o;
  }
}

extern "C" void kernel_launch(void* const* d_in, const int* in_sizes, int n_in,
                              void* d_out, int out_size, void* d_ws, size_t ws_size,
                              hipStream_t stream) {
  const float* x  = (const float*)d_in[0];
  const float* gg = (const float*)d_in[1];
  const float* gb = (const float*)d_in[2];
  const float* wq = (const float*)d_in[3];
  const float* bq = (const float*)d_in[4];
  const float* wk = (const float*)d_in[5];
  const float* bk = (const float*)d_in[6];
  const float* wv = (const float*)d_in[7];
  const float* bv = (const float*)d_in[8];
  const float* wp = (const float*)d_in[9];
  const float* bp = (const float*)d_in[10];
  float* out = (float*)d_out;

  char* ws = (char*)d_ws;
  const size_t MATS = (size_t)BB * NN * CC;
  u16* wbf  = (u16*)ws;                 // 512 KB
  u16* xn   = (u16*)(ws + (512 << 10)); // 8 MB
  u16* Qtm  = xn + MATS;
  u16* Ktm  = Qtm + MATS;
  u16* Vcm  = Ktm + MATS;
  u16* Otm  = xn;                       // reuse (xn dead after V GEMM)
  uint32_t* Op32 = (uint32_t*)(Vcm + MATS);       // 16*128*4096*4 = 33.5 MB
  float* Lpart   = (float*)(Op32 + (size_t)16*128*NN);  // 256 KB
  float* part    = Lpart + (size_t)16*NN;         // 512 floats

  wcvt_kernel<<<dim3(64, 4), 256, 0, stream>>>(wq, wk, wv, wp, wbf);
  gn_part_kernel<<<dim3(32, 8), 256, 0, stream>>>(x, part);
  gn_apply_kernel<<<dim3(64, 4), 256, 0, stream>>>(x, part, gg, gb, xn);
  gemm_tm_kernel<<<dim3(64, 4, 4), 256, 0, stream>>>(xn, wbf + 0*65536, bq, Qtm);
  gemm_tm_kernel<<<dim3(64, 4, 4), 256, 0, stream>>>(xn, wbf + 1*65536, bk, Ktm);
  gemm_cm_bf16_kernel<<<dim3(64, 4, 4), 256, 0, stream>>>(xn, wbf + 2*65536, bv, Vcm);
  flash_kernel<<<512, 256, 0, stream>>>(Qtm, Ktm, Vcm, Op32, Lpart);
  merge_kernel<<<dim3(16, 4, 4), 256, 0, stream>>>(Op32, Lpart, Otm);
  gemm_cm_proj_kernel<<<dim3(64, 4, 4), 256, 0, stream>>>(Otm, wbf + 3*65536, bp, out, x);
}

// Round 4
// 159.017 us; speedup vs baseline: 2.2236x; 1.2777x over previous
//
#include <hip/hip_runtime.h>
#include <stdint.h>

#define BB 4
#define CC 256
#define NN 4096
#define GG 8

typedef unsigned short u16;
typedef __attribute__((ext_vector_type(4))) float f32x4;
typedef __attribute__((ext_vector_type(16))) float f32x16;
typedef __attribute__((ext_vector_type(8))) short s16x8;
typedef __attribute__((ext_vector_type(4))) u16 u16x4;
typedef __attribute__((ext_vector_type(8))) u16 u16x8;

__device__ __forceinline__ u16 f2bf(float f) {
  union { float f; uint32_t u; } v; v.f = f;
  return (u16)((v.u + 0x7FFFu + ((v.u >> 16) & 1u)) >> 16);
}
__device__ __forceinline__ float bf2f(uint32_t u) {
  union { uint32_t u; float f; } v; v.u = u << 16;
  return v.f;
}

__device__ __forceinline__ void async16(const void* g, void* l) {
  __builtin_amdgcn_global_load_lds(
      (const __attribute__((address_space(1))) void*)g,
      (__attribute__((address_space(3))) void*)l, 16, 0, 0);
}

// ---------------- weight f32 -> bf16 ----------------
__global__ __launch_bounds__(256) void wcvt_kernel(
    const float* __restrict__ w0, const float* __restrict__ w1,
    const float* __restrict__ w2, const float* __restrict__ w3,
    u16* __restrict__ dst) {
  const float* src = (blockIdx.y == 0) ? w0 : (blockIdx.y == 1) ? w1
                   : (blockIdx.y == 2) ? w2 : w3;
  int i = blockIdx.x * 256 + threadIdx.x;
  f32x4 v = ((const f32x4*)src)[i];
  u16x4 o;
  o[0] = f2bf(v[0]); o[1] = f2bf(v[1]); o[2] = f2bf(v[2]); o[3] = f2bf(v[3]);
  ((u16x4*)(dst + (size_t)blockIdx.y * 65536))[i] = o;
}

// ---------------- GroupNorm partial sums: 256 blocks ----------------
__global__ __launch_bounds__(256) void gn_part_kernel(
    const float* __restrict__ x, float* __restrict__ part) {
  int bg = blockIdx.x, seg = blockIdx.y;  // 32 x 8
  const f32x4* xp = (const f32x4*)(x + (size_t)bg * 131072 + seg * 16384);
  float s = 0.f, ss = 0.f;
  for (int i = threadIdx.x; i < 4096; i += 256) {
    f32x4 v = xp[i];
    s += v[0] + v[1] + v[2] + v[3];
    ss += v[0]*v[0] + v[1]*v[1] + v[2]*v[2] + v[3]*v[3];
  }
  for (int d = 1; d < 64; d <<= 1) {
    s += __shfl_xor(s, d, 64);
    ss += __shfl_xor(ss, d, 64);
  }
  __shared__ float red[8];
  int w = threadIdx.x >> 6, lane = threadIdx.x & 63;
  if (lane == 0) { red[w*2] = s; red[w*2+1] = ss; }
  __syncthreads();
  if (threadIdx.x == 0) {
    part[(bg*8 + seg)*2]     = red[0]+red[2]+red[4]+red[6];
    part[(bg*8 + seg)*2 + 1] = red[1]+red[3]+red[5]+red[7];
  }
}

// ======== fused GN-apply + QKV GEMM ========
// grid (64 n-tiles, 4 b) x 512 thr. Outputs Qtm/Ktm token-major, Vcm channel-major.
__global__ __launch_bounds__(512) void gnqkv_kernel(
    const float* __restrict__ x, const float* __restrict__ part,
    const float* __restrict__ gamma, const float* __restrict__ beta,
    const u16* __restrict__ wbf,
    const float* __restrict__ bq, const float* __restrict__ bk,
    const float* __restrict__ bv,
    u16* __restrict__ Qtm, u16* __restrict__ Ktm, u16* __restrict__ Vcm) {
  __shared__ float gstat[16];
  __shared__ char t1[32768];  // [256 c][64 n] bf16, XOR-swizzled
  __shared__ char t2[32768];  // [64 n][256 c] bf16, row-swizzled for B-frags
  const int b = blockIdx.y, n0 = blockIdx.x * 64, t = threadIdx.x;
  if (t < 8) {
    float S = 0.f, SS = 0.f;
    for (int seg = 0; seg < 8; ++seg) {
      S  += part[((b*8 + t)*8 + seg)*2];
      SS += part[((b*8 + t)*8 + seg)*2 + 1];
    }
    float mean = S * (1.0f/131072.0f);
    float var = SS * (1.0f/131072.0f) - mean*mean;
    gstat[t*2] = mean;
    gstat[t*2+1] = rsqrtf(var + 1e-5f);
  }
  __syncthreads();
  // phase A: GN -> t1 [c][n]
  for (int p = 0; p < 8; ++p) {
    int c = p*32 + (t >> 4);
    int n4 = (t & 15) * 4;
    f32x4 v = *(const f32x4*)(x + ((size_t)b*CC + c)*NN + n0 + n4);
    float mean = gstat[(c>>5)*2], rstd = gstat[(c>>5)*2+1];
    float ga = gamma[c] * rstd;
    float be = beta[c] - mean * ga;
    u16x4 o;
    o[0]=f2bf(v[0]*ga+be); o[1]=f2bf(v[1]*ga+be);
    o[2]=f2bf(v[2]*ga+be); o[3]=f2bf(v[3]*ga+be);
    int swz = (((c & 7) ^ ((c >> 3) & 7)) << 4);
    *(u16x4*)(t1 + c*128 + ((n4*2) ^ swz)) = o;
  }
  __syncthreads();
  // phase B: transpose -> t2 [n][c]
  for (int p = 0; p < 4; ++p) {
    int n = p*16 + (t >> 5);
    int c0 = (t & 31) * 8;
    u16x8 o;
#pragma unroll
    for (int j = 0; j < 8; ++j) {
      int c = c0 + j;
      int swz = (((c & 7) ^ ((c >> 3) & 7)) << 4);
      o[j] = *(const u16*)(t1 + c*128 + ((n*2) ^ swz));
    }
    *(u16x8*)(t2 + n*512 + ((c0*2) ^ ((n & 7) << 4))) = o;
  }
  __syncthreads();
  // phase C: three sub-GEMMs from t2
  const int lane = t & 63, w = t >> 6;
  const int wn = w >> 2, wo = w & 3;
  const int hi = lane >> 4, lo = lane & 15;
#pragma unroll
  for (int mat = 0; mat < 3; ++mat) {
    const u16* wm = wbf + mat*65536;
    f32x4 acc[2][4] = {};
    for (int kc = 0; kc < 8; ++kc) {
      s16x8 xf[2];
#pragma unroll
      for (int nf = 0; nf < 2; ++nf) {
        int n = wn*32 + nf*16 + lo;
        xf[nf] = *(const s16x8*)(t2 + n*512 + ((kc*64 + hi*16) ^ ((n & 7) << 4)));
      }
#pragma unroll
      for (int of = 0; of < 4; ++of) {
        int o = wo*64 + of*16 + lo;
        s16x8 wf = *(const s16x8*)(wm + (size_t)o*256 + kc*32 + hi*8);
        if (mat < 2) {
          acc[0][of] = __builtin_amdgcn_mfma_f32_16x16x32_bf16(xf[0], wf, acc[0][of], 0, 0, 0);
          acc[1][of] = __builtin_amdgcn_mfma_f32_16x16x32_bf16(xf[1], wf, acc[1][of], 0, 0, 0);
        } else {
          acc[0][of] = __builtin_amdgcn_mfma_f32_16x16x32_bf16(wf, xf[0], acc[0][of], 0, 0, 0);
          acc[1][of] = __builtin_amdgcn_mfma_f32_16x16x32_bf16(wf, xf[1], acc[1][of], 0, 0, 0);
        }
      }
    }
    if (mat < 2) {
      u16* Y = (mat == 0) ? Qtm : Ktm;
      const float* bias = (mat == 0) ? bq : bk;
#pragma unroll
      for (int nf = 0; nf < 2; ++nf)
#pragma unroll
        for (int of = 0; of < 4; ++of) {
          int oc = wo*64 + of*16 + lo;
          float bvv = bias[oc];
#pragma unroll
          for (int r = 0; r < 4; ++r) {
            int n = n0 + wn*32 + nf*16 + hi*4 + r;
            Y[((size_t)b*NN + n)*CC + oc] = f2bf(acc[nf][of][r] + bvv);
          }
        }
    } else {
#pragma unroll
      for (int nf = 0; nf < 2; ++nf)
#pragma unroll
        for (int of = 0; of < 4; ++of)
#pragma unroll
          for (int r = 0; r < 4; ++r) {
            int oc = wo*64 + of*16 + hi*4 + r;
            int n = n0 + wn*32 + nf*16 + lo;
            Vcm[((size_t)b*CC + oc)*NN + n] = f2bf(acc[nf][of][r] + bv[oc]);
          }
    }
  }
}

// ======== flash attention v4: dbuf m-tile=32, counted vmcnt, 2 barriers/iter ====
// Q[b][n][c], K[b][m][c], V[b][c][m] -> Op32 (bf16-pair [pb][c/2][q]), Lpart
__global__ __launch_bounds__(256, 2) void flash_kernel(
    const u16* __restrict__ Q, const u16* __restrict__ K,
    const u16* __restrict__ V, uint32_t* __restrict__ Op32,
    float* __restrict__ Lpart) {
  __shared__ char kl[2][16384];  // [32 cslot][32 m][16B]
  __shared__ char vl[2][16384];  // [4 mslot][256 c][16B]
  const int bid = blockIdx.x;
  const int b    = bid & 3;
  const int part = ((bid >> 2) & 1) | (((bid >> 8) & 1) << 1);
  const int qb   = (bid >> 3) & 31;
  const int tid = threadIdx.x;
  const int lane = tid & 63;
  const int w = tid >> 6;
  const int cl = lane & 31;
  const int h = lane >> 5;
  const int q = qb*128 + w*32 + cl;

  s16x8 qreg[16];
  {
    const u16* qp = Q + ((size_t)b*NN + q)*CC + h*8;
#pragma unroll
    for (int kc = 0; kc < 16; ++kc) qreg[kc] = *(const s16x8*)(qp + kc*16);
  }
  f32x16 oacc[8];
#pragma unroll
  for (int i = 0; i < 8; ++i) oacc[i] = (f32x16)0.f;
  float Lp = 0.f;

  const char* kbase = (const char*)(K + (size_t)b*NN*CC);
  const char* vbase = (const char*)(V + (size_t)b*CC*NN);
  const int mbase = part*1024;

  auto stage = [&](int buf, int m0) {
#pragma unroll
    for (int p = 0; p < 4; ++p)   // K: [cslot][m][16B]
      async16(kbase + (size_t)(m0 + (tid & 31))*512 + ((tid >> 5) + p*8)*16,
              kl[buf] + p*4096 + tid*16);
#pragma unroll
    for (int p = 0; p < 4; ++p)   // V: [mslot][c][16B]
      async16(vbase + (size_t)tid*8192 + (size_t)m0*2 + p*16,
              vl[buf] + p*4096 + tid*16);
  };

  stage(0, mbase);
  stage(1, mbase + 32);

  const float SC = 0.0901684857f;  // log2(e)/16

  for (int it = 0; it < 32; ++it) {
    const int cur = it & 1;
    if (it == 31) asm volatile("s_waitcnt vmcnt(0)" ::: "memory");
    else          asm volatile("s_waitcnt vmcnt(8)" ::: "memory");
    __builtin_amdgcn_s_barrier();
    asm volatile("" ::: "memory");  // no LDS reads above the barrier

    // S^T = K . Q^T : one 32x32 tile (32 m-rows x 32 q-cols)
    f32x16 s0 = (f32x16)0.f;
    __builtin_amdgcn_s_setprio(1);
#pragma unroll
    for (int kc = 0; kc < 16; ++kc) {
      s16x8 kf = *(const s16x8*)(kl[cur] + (kc*2 + h)*512 + cl*16);
      s0 = __builtin_amdgcn_mfma_f32_32x32x16_bf16(kf, qreg[kc], s0, 0, 0, 0);
    }
    __builtin_amdgcn_s_setprio(0);

    // M-free softmax + in-register P^T B-fragments
    s16x8 pf[2];
#pragma unroll
    for (int half = 0; half < 2; ++half) {
      float pe[8];
#pragma unroll
      for (int j = 0; j < 8; ++j) {
        float p = exp2f(s0[half*8 + j] * SC);
        pe[j] = p;
        Lp += p;
      }
      uint32_t a0, a1, a2, a3;
      asm("v_cvt_pk_bf16_f32 %0, %1, %2" : "=v"(a0) : "v"(pe[0]), "v"(pe[1]));
      asm("v_cvt_pk_bf16_f32 %0, %1, %2" : "=v"(a1) : "v"(pe[2]), "v"(pe[3]));
      asm("v_cvt_pk_bf16_f32 %0, %1, %2" : "=v"(a2) : "v"(pe[4]), "v"(pe[5]));
      asm("v_cvt_pk_bf16_f32 %0, %1, %2" : "=v"(a3) : "v"(pe[6]), "v"(pe[7]));
      asm("v_permlane32_swap_b32 %0, %1" : "+v"(a0), "+v"(a2));
      asm("v_permlane32_swap_b32 %0, %1" : "+v"(a1), "+v"(a3));
      union { uint32_t w[4]; s16x8 v; } u;
      u.w[0] = a0; u.w[1] = a1; u.w[2] = a2; u.w[3] = a3;
      pf[half] = u.v;
    }

    // O^T += V^T . P^T
    __builtin_amdgcn_s_setprio(1);
#pragma unroll
    for (int ks = 0; ks < 2; ++ks) {
#pragma unroll
      for (int ct = 0; ct < 8; ++ct) {
        s16x8 vf = *(const s16x8*)(vl[cur] + (ks*2 + h)*4096 + (ct*32 + cl)*16);
        oacc[ct] = __builtin_amdgcn_mfma_f32_32x32x16_bf16(vf, pf[ks], oacc[ct], 0, 0, 0);
      }
    }
    __builtin_amdgcn_s_setprio(0);
    __builtin_amdgcn_s_barrier();   // all waves done reading buf cur
    if (it < 30) stage(cur, mbase + (it + 2)*32);
  }

  // epilogue: partial L and partial O^T (bf16 pairs along c)
  float Lq = Lp + __shfl_xor(Lp, 32, 64);
  const int pb = part*4 + b;
  if (lane < 32) Lpart[(size_t)pb*NN + q] = Lq;
  const size_t basePB = (size_t)pb * 128 * NN;
#pragma unroll
  for (int ct = 0; ct < 8; ++ct) {
#pragma unroll
    for (int i2 = 0; i2 < 8; ++i2) {
      const int i = i2*2;
      float lo_ = oacc[ct][i], hi_ = oacc[ct][i+1];
      uint32_t pk;
      asm("v_cvt_pk_bf16_f32 %0, %1, %2" : "=v"(pk) : "v"(lo_), "v"(hi_));
      const int cp = ct*16 + ((i&3)>>1) + 4*(i>>2) + 2*h;  // c/2
      Op32[basePB + (size_t)cp*NN + q] = pk;
    }
  }
}

// ======== fused merge + proj GEMM + bias + fp32 residual ========
// grid (64 m-tiles, 4 b) x 512 thr
__global__ __launch_bounds__(512) void proj_kernel(
    const uint32_t* __restrict__ Op32, const float* __restrict__ Lpart,
    const u16* __restrict__ wp, const float* __restrict__ bp,
    const float* __restrict__ resid, float* __restrict__ out) {
  __shared__ char t2[32768];  // [64 m][256 c] bf16, row-swizzled
  const int b = blockIdx.y, m0 = blockIdx.x * 64, t = threadIdx.x;
  // phase A: merge 4 partials -> normalized bf16 tile
  {
    const int q = m0 + (t & 63);
    const int m = t & 63;
    const int cg = t >> 6;  // 0..7
    float L = 0.f;
#pragma unroll
    for (int p = 0; p < 4; ++p) L += Lpart[(size_t)(p*4 + b)*NN + q];
    const float inv = 1.0f / L;
#pragma unroll
    for (int i = 0; i < 16; ++i) {
      const int cp = cg*16 + i;
      float v0 = 0.f, v1 = 0.f;
#pragma unroll
      for (int p = 0; p < 4; ++p) {
        uint32_t pk = Op32[(size_t)(p*4 + b)*128*NN + (size_t)cp*NN + q];
        v0 += bf2f(pk & 0xffffu);
        v1 += bf2f(pk >> 16);
      }
      v0 *= inv; v1 *= inv;
      uint32_t opk;
      asm("v_cvt_pk_bf16_f32 %0, %1, %2" : "=v"(opk) : "v"(v0), "v"(v1));
      *(uint32_t*)(t2 + m*512 + ((cp*4) ^ ((m & 7) << 4))) = opk;
    }
  }
  __syncthreads();
  // phase B: GEMM (A = Wp rows o, B = tile rows m) -> out[b][o][m]
  const int lane = t & 63, w = t >> 6;
  const int wm = w >> 2, wo = w & 3;
  const int hi = lane >> 4, lo = lane & 15;
  f32x4 acc[2][4] = {};
  for (int kc = 0; kc < 8; ++kc) {
    s16x8 xf[2];
#pragma unroll
    for (int mf = 0; mf < 2; ++mf) {
      int m = wm*32 + mf*16 + lo;
      xf[mf] = *(const s16x8*)(t2 + m*512 + ((kc*64 + hi*16) ^ ((m & 7) << 4)));
    }
#pragma unroll
    for (int of = 0; of < 4; ++of) {
      int o = wo*64 + of*16 + lo;
      s16x8 wf = *(const s16x8*)(wp + (size_t)o*256 + kc*32 + hi*8);
      acc[0][of] = __builtin_amdgcn_mfma_f32_16x16x32_bf16(wf, xf[0], acc[0][of], 0, 0, 0);
      acc[1][of] = __builtin_amdgcn_mfma_f32_16x16x32_bf16(wf, xf[1], acc[1][of], 0, 0, 0);
    }
  }
#pragma unroll
  for (int mf = 0; mf < 2; ++mf)
#pragma unroll
    for (int of = 0; of < 4; ++of) {
      int oc0 = wo*64 + of*16 + hi*4;
#pragma unroll
      for (int r = 0; r < 4; ++r) {
        int m = m0 + wm*32 + mf*16 + lo;
        size_t idx = ((size_t)b*CC + oc0 + r)*NN + m;
        out[idx] = acc[mf][of][r] + bp[oc0 + r] + resid[idx];
      }
    }
}

extern "C" void kernel_launch(void* const* d_in, const int* in_sizes, int n_in,
                              void* d_out, int out_size, void* d_ws, size_t ws_size,
                              hipStream_t stream) {
  const float* x  = (const float*)d_in[0];
  const float* gg = (const float*)d_in[1];
  const float* gb = (const float*)d_in[2];
  const float* wq = (const float*)d_in[3];
  const float* bq = (const float*)d_in[4];
  const float* wk = (const float*)d_in[5];
  const float* bk = (const float*)d_in[6];
  const float* wv = (const float*)d_in[7];
  const float* bv = (const float*)d_in[8];
  const float* wp = (const float*)d_in[9];
  const float* bp = (const float*)d_in[10];
  float* out = (float*)d_out;

  char* ws = (char*)d_ws;
  const size_t MATS = (size_t)BB * NN * CC;
  u16* wbf  = (u16*)ws;                 // 512 KB (Q,K,V,P bf16 weights)
  u16* Qtm  = (u16*)(ws + (512 << 10)); // 8 MB token-major
  u16* Ktm  = Qtm + MATS;               // 8 MB token-major
  u16* Vcm  = Ktm + MATS;               // 8 MB channel-major
  uint32_t* Op32 = (uint32_t*)(Vcm + MATS);            // 33.5 MB partials
  float* Lpart   = (float*)(Op32 + (size_t)16*128*NN); // 256 KB
  float* part    = Lpart + (size_t)16*NN;              // 512 floats

  wcvt_kernel<<<dim3(64, 4), 256, 0, stream>>>(wq, wk, wv, wp, wbf);
  gn_part_kernel<<<dim3(32, 8), 256, 0, stream>>>(x, part);
  gnqkv_kernel<<<dim3(64, 4), 512, 0, stream>>>(x, part, gg, gb, wbf,
                                                bq, bk, bv, Qtm, Ktm, Vcm);
  flash_kernel<<<512, 256, 0, stream>>>(Qtm, Ktm, Vcm, Op32, Lpart);
  proj_kernel<<<dim3(64, 4), 512, 0, stream>>>(Op32, Lpart, wbf + 3*65536,
                                               bp, x, out);
}